// Round 9
// baseline (481.163 us; speedup 1.0000x reference)
//
#include <hip/hip_runtime.h>
#include <hip/hip_bf16.h>
#include <math.h>

#define BB 4
#define CC 192
#define HH 56
#define WW 56
#define HWW 3136
#define NBLK 448
#define SLOT_STRIDE 32           // dwords = 128 B per slot

typedef __attribute__((ext_vector_type(8))) short short8;
typedef __attribute__((ext_vector_type(4))) float f32x4;

__device__ __forceinline__ unsigned short f2b(float f) {
    __hip_bfloat16 h = __float2bfloat16(f);
    return __builtin_bit_cast(unsigned short, h);
}
__device__ __forceinline__ float b2f(unsigned short u) {
    unsigned int x = ((unsigned int)u) << 16;
    return __builtin_bit_cast(float, x);
}
__device__ __forceinline__ void fma4(float4& a, float w, const float4& x) {
    a.x += w * x.x; a.y += w * x.y; a.z += w * x.z; a.w += w * x.w;
}

// RMW-free grid barrier: per-block slot stores + block-0 gather + release flag.
// slots: NBLK slots, 128B apart. rel: one word. All zeroed by k_init.
__device__ __forceinline__ void gridbar(unsigned* slots, unsigned* rel,
                                        int bid, int tid) {
    __threadfence();                 // make this block's stores agent-visible
    __syncthreads();
    if (bid == 0) {
        while (true) {
            unsigned a = 1u, b = 1u;
            if (tid + 1 < NBLK)
                a = __hip_atomic_load(&slots[(tid + 1) * SLOT_STRIDE],
                                      __ATOMIC_RELAXED, __HIP_MEMORY_SCOPE_AGENT);
            if (tid + 257 < NBLK)
                b = __hip_atomic_load(&slots[(tid + 257) * SLOT_STRIDE],
                                      __ATOMIC_RELAXED, __HIP_MEMORY_SCOPE_AGENT);
            if (__syncthreads_and((int)(a != 0u && b != 0u))) break;
            __builtin_amdgcn_s_sleep(2);
        }
        if (tid == 0)
            __hip_atomic_store(rel, 1u, __ATOMIC_RELEASE, __HIP_MEMORY_SCOPE_AGENT);
    } else {
        if (tid == 0) {
            __hip_atomic_store(&slots[bid * SLOT_STRIDE], 1u,
                               __ATOMIC_RELEASE, __HIP_MEMORY_SCOPE_AGENT);
            while (__hip_atomic_load(rel, __ATOMIC_ACQUIRE,
                                     __HIP_MEMORY_SCOPE_AGENT) == 0u)
                __builtin_amdgcn_s_sleep(2);
        }
        __syncthreads();
    }
    __threadfence();                 // acquire side
    __syncthreads();
}

// Zero 3 barrier phases: 3 * (NBLK*SLOT_STRIDE) slot dwords + 3 flag dwords.
#define BAR_PHASE (NBLK * SLOT_STRIDE)
__global__ __launch_bounds__(256) void k_init(unsigned* bar) {
    int i = blockIdx.x * 256 + threadIdx.x;
    int total = 3 * BAR_PHASE + 64;
    if (i < total) bar[i] = 0u;
}

// ---------------------------------------------------------------------------
// Mega-kernel: P0 transpose + weight-split | P1 scores | P2 acc | P3 conv
// ---------------------------------------------------------------------------
__global__ __launch_bounds__(256, 2) void k_mega(
        const float* __restrict__ x, const float* __restrict__ cw,
        const float* __restrict__ cb, const float* __restrict__ gma,
        const float* __restrict__ bta, const float* __restrict__ mea,
        const float* __restrict__ var, float* __restrict__ y,
        float* __restrict__ xt, float* __restrict__ sp,
        unsigned short* __restrict__ oHh, unsigned short* __restrict__ oHl,
        unsigned short* __restrict__ oWh, unsigned short* __restrict__ oWl,
        unsigned short* __restrict__ cwh, unsigned short* __restrict__ cwl,
        unsigned* __restrict__ bar) {
    __shared__ __align__(16) char smem[36864];
    int tid = threadIdx.x;
    int bid0 = blockIdx.x;
    unsigned* flags = bar + 3 * BAR_PHASE;

    // ---------------- P0: transpose x -> xt, split conv_w (K=576) ----------
    {
        float (*tile)[33] = (float (*)[33])smem;
        int tx = tid & 31, ty = tid >> 5;
        for (int id = bid0; id < 2352; id += NBLK) {
            int b = id / 588, rem = id % 588;
            int by = rem / 98, bx = rem % 98;
            int p0 = bx * 32, c0 = by * 32;
            __syncthreads();
#pragma unroll
            for (int i = 0; i < 4; i++) {
                int c = c0 + ty + 8 * i;
                tile[ty + 8 * i][tx] = x[(b * CC + c) * HWW + p0 + tx];
            }
            __syncthreads();
#pragma unroll
            for (int i = 0; i < 4; i++) {
                int p = p0 + ty + 8 * i;
                xt[(size_t)(b * HWW + p) * CC + c0 + tx] = tile[tx][ty + 8 * i];
            }
        }
        for (int i = bid0 * 256 + tid; i < CC * 576; i += NBLK * 256) {
            int o = i / 576, k = i % 576;
            int ks = (k >= 384) ? (k - 192) : k;
            float v = cw[o * 384 + ks];
            unsigned short hi = f2b(v);
            cwh[i] = hi;
            cwl[i] = f2b(v - b2f(hi));
        }
    }
    gridbar(bar, &flags[0], bid0, tid);

    // ---------------- P1: scores (pair symmetry), 4 virtual blocks --------
    {
        float* Xs = (float*)smem;     // 28 rows x 96ch (+4 pad) = 11.2 KB
        const float K2 = 0.38490017945975050f;  // 2/sqrt(27)
#pragma unroll 1
        for (int it = 0; it < 4; it++) {
            int vb = bid0 + NBLK * it;            // 0..1791
            bool isH = vb < 896;
            int lid = isH ? vb : vb - 896;
            int half = lid & 1;
            int rp = (lid >> 1) & 1;
            int cb2 = lid >> 2;                   // 0..223
            int b = cb2 / 56, l0 = cb2 % 56;
            int r0 = rp * 2;

            const float* src = xt + (size_t)(b * HWW) * CC + half * 96;
            __syncthreads();
            for (int idx = tid; idx < 28 * 24; idx += 256) {
                int t2 = idx / 24, cq = idx % 24;
                int pi = (r0 + t2 / 14) + 4 * (t2 % 14);
                int pix = isH ? (pi * WW + l0) : (l0 * WW + pi);
                float4 v = *(const float4*)(src + (size_t)pix * CC + cq * 4);
                *(float4*)&Xs[t2 * 100 + cq * 4] = v;
            }
            __syncthreads();

            int perCls = isH ? 105 : 91;
            if (tid < 2 * perCls) {
                int cls = tid / perCls, p = tid % perCls;
                int a, bb;
                if (isH) {
                    a = (int)((sqrtf((float)(8 * p + 1)) - 1.0f) * 0.5f);
                    bb = p - (a * (a + 1)) / 2;
                } else {
                    int ap = (int)((sqrtf((float)(8 * p + 1)) - 1.0f) * 0.5f);
                    bb = p - (ap * (ap + 1)) / 2;
                    a = ap + 1;
                }
                const float* pA = &Xs[(cls * 14 + a) * 100];
                const float* pB = &Xs[(cls * 14 + bb) * 100];
                float s0 = 0.f, s1 = 0.f, s2 = 0.f, s3 = 0.f;
#pragma unroll
                for (int q = 0; q < 24; q++) {
                    float4 av = *(const float4*)(pA + q * 4);
                    float4 bv = *(const float4*)(pB + q * 4);
                    s0 += __builtin_amdgcn_rcpf(__expf(av.x * bv.x * K2) + 1.0f);
                    s1 += __builtin_amdgcn_rcpf(__expf(av.y * bv.y * K2) + 1.0f);
                    s2 += __builtin_amdgcn_rcpf(__expf(av.z * bv.z * K2) + 1.0f);
                    s3 += __builtin_amdgcn_rcpf(__expf(av.w * bv.w * K2) + 1.0f);
                }
                float s = 96.0f - 2.0f * (s0 + s1 + s2 + s3);  // sum tanh
                int r = r0 + cls;
                size_t base = (size_t)(half * BB + b) * HWW;
                if (isH) {
                    int i1 = a - bb;
                    int h1 = r + 4 * a, h2 = r + 4 * bb;
                    sp[(base + h1 * WW + l0) * 32 + i1] = s;
                    if (a != bb) sp[(base + h2 * WW + l0) * 32 + (14 - i1)] = s;
                } else {
                    int d = a - bb;
                    int w1 = r + 4 * a, w2 = r + 4 * bb;
                    sp[(base + l0 * WW + w1) * 32 + 14 + (d - 1)] = s;
                    sp[(base + l0 * WW + w2) * 32 + 14 + (13 - d)] = s;
                }
            }
        }
    }
    gridbar(bar + BAR_PHASE, &flags[8], bid0, tid);

    // ---------------- P2: softmax + weighted accumulation ------------------
    {
        float* Wt = (float*)smem;     // 14*56 floats
        bool isH = bid0 < 224;
        int lid = isH ? bid0 : bid0 - 224;
        int b = lid / 56, l0 = lid % 56;

        if (tid < 56) {
            int pix = isH ? (tid * WW + l0) : (l0 * WW + tid);
            const float4* p0 = (const float4*)&sp[((size_t)(0 * BB + b) * HWW + pix) * 32];
            const float4* p1 = (const float4*)&sp[((size_t)(1 * BB + b) * HWW + pix) * 32];
            float sc[28];
#pragma unroll
            for (int j = 0; j < 7; j++) {
                float4 u = p0[j], v = p1[j];
                sc[4 * j + 0] = u.x + v.x; sc[4 * j + 1] = u.y + v.y;
                sc[4 * j + 2] = u.z + v.z; sc[4 * j + 3] = u.w + v.w;
            }
            float mx = -1e30f;
#pragma unroll
            for (int s = 0; s < 27; s++) mx = fmaxf(mx, sc[s]);
            float sum = 0.f;
#pragma unroll
            for (int s = 0; s < 27; s++) { sc[s] = __expf(sc[s] - mx); sum += sc[s]; }
            float inv = __builtin_amdgcn_rcpf(sum);
            if (isH) {
#pragma unroll
                for (int i = 0; i < 14; i++) Wt[i * 56 + tid] = sc[i] * inv;
            } else {
#pragma unroll
                for (int j = 0; j < 13; j++) Wt[j * 56 + tid] = sc[14 + j] * inv;
            }
        }
        __syncthreads();
        if (tid < 192) {
            int r = tid & 3, q = tid >> 2;
            float4 in[14];
#pragma unroll
            for (int t = 0; t < 14; t++) {
                int pix = isH ? ((r + 4 * t) * WW + l0) : (l0 * WW + (r + 4 * t));
                in[t] = *(const float4*)(xt + (size_t)(b * HWW + pix) * CC + q * 4);
            }
            float4 acc[14] = {};
            if (isH) {
#pragma unroll
                for (int i = 0; i < 14; i++)
#pragma unroll
                    for (int a = 0; a < 14; a++)
                        fma4(acc[a], Wt[i * 56 + (r + 4 * a)], in[(a - i + 14) % 14]);
            } else {
#pragma unroll
                for (int j = 0; j < 13; j++)
#pragma unroll
                    for (int a = 0; a < 14; a++)
                        fma4(acc[a], Wt[j * 56 + (r + 4 * a)], in[(a - j - 1 + 14) % 14]);
            }
            unsigned short* dh = isH ? oHh : oWh;
            unsigned short* dl = isH ? oHl : oWl;
#pragma unroll
            for (int a = 0; a < 14; a++) {
                int pix = isH ? ((r + 4 * a) * WW + l0) : (l0 * WW + (r + 4 * a));
                size_t o = (size_t)(b * HWW + pix) * CC + q * 4;
                ushort4 hi4, lo4;
                hi4.x = f2b(acc[a].x); lo4.x = f2b(acc[a].x - b2f(hi4.x));
                hi4.y = f2b(acc[a].y); lo4.y = f2b(acc[a].y - b2f(hi4.y));
                hi4.z = f2b(acc[a].z); lo4.z = f2b(acc[a].z - b2f(hi4.z));
                hi4.w = f2b(acc[a].w); lo4.w = f2b(acc[a].w - b2f(hi4.w));
                *(ushort4*)(dh + o) = hi4;
                *(ushort4*)(dl + o) = lo4;
            }
        }
    }
    gridbar(bar + 2 * BAR_PHASE, &flags[16], bid0, tid);

    // ---------------- P3: split-bf16 MFMA conv, A=[x|oH|oW], K=576 ---------
    {
        unsigned short* Ah = (unsigned short*)smem;
        unsigned short* Al = Ah + 64 * 72;
        unsigned short* Bh = Ah + 2 * 64 * 72;
        unsigned short* Bl = Ah + 3 * 64 * 72;
        float* Ds = (float*)smem;
        int lane = tid & 63, wv = tid >> 6;
#pragma unroll 1
        for (int v = bid0; v < 588; v += NBLK) {
            int bm = (v % 196) * 64, bn = (v / 196) * 64;
            __syncthreads();
            f32x4 acc[4] = {{0,0,0,0},{0,0,0,0},{0,0,0,0},{0,0,0,0}};
            for (int kc9 = 0; kc9 < 9; kc9++) {
#pragma unroll
                for (int r2 = 0; r2 < 2; r2++) {
                    int idx = tid + r2 * 256;
                    int m = idx >> 3, kq = idx & 7;
                    if (kc9 < 3) {
                        const float* s = xt + (size_t)(bm + m) * CC + kc9 * 64 + kq * 8;
                        float4 v0 = *(const float4*)s;
                        float4 v1 = *(const float4*)(s + 4);
                        float vv[8] = {v0.x, v0.y, v0.z, v0.w, v1.x, v1.y, v1.z, v1.w};
                        unsigned short hi[8], lo[8];
#pragma unroll
                        for (int e = 0; e < 8; e++) {
                            hi[e] = f2b(vv[e]);
                            lo[e] = f2b(vv[e] - b2f(hi[e]));
                        }
                        *(short8*)&Ah[m * 72 + kq * 8] = *(short8*)hi;
                        *(short8*)&Al[m * 72 + kq * 8] = *(short8*)lo;
                    } else {
                        const unsigned short* sh;
                        const unsigned short* sl;
                        int coff;
                        if (kc9 < 6) { sh = oHh; sl = oHl; coff = (kc9 - 3) * 64; }
                        else         { sh = oWh; sl = oWl; coff = (kc9 - 6) * 64; }
                        size_t ao = (size_t)(bm + m) * CC + coff + kq * 8;
                        *(short8*)&Ah[m * 72 + kq * 8] = *(const short8*)(sh + ao);
                        *(short8*)&Al[m * 72 + kq * 8] = *(const short8*)(sl + ao);
                    }
                    size_t bo = (size_t)(bn + m) * 576 + kc9 * 64 + kq * 8;
                    *(short8*)&Bh[m * 72 + kq * 8] = *(const short8*)(cwh + bo);
                    *(short8*)&Bl[m * 72 + kq * 8] = *(const short8*)(cwl + bo);
                }
                __syncthreads();
                int n0 = wv * 16;
                int k8 = lane >> 4;
                int col = lane & 15;
#pragma unroll
                for (int ks = 0; ks < 64; ks += 32) {
                    int koff = ks + k8 * 8;
                    short8 bfh = *(const short8*)&Bh[(n0 + col) * 72 + koff];
                    short8 bfl = *(const short8*)&Bl[(n0 + col) * 72 + koff];
#pragma unroll
                    for (int fm = 0; fm < 4; fm++) {
                        short8 afh = *(const short8*)&Ah[(fm * 16 + col) * 72 + koff];
                        short8 afl = *(const short8*)&Al[(fm * 16 + col) * 72 + koff];
                        acc[fm] = __builtin_amdgcn_mfma_f32_16x16x32_bf16(afh, bfh, acc[fm], 0, 0, 0);
                        acc[fm] = __builtin_amdgcn_mfma_f32_16x16x32_bf16(afl, bfh, acc[fm], 0, 0, 0);
                        acc[fm] = __builtin_amdgcn_mfma_f32_16x16x32_bf16(afh, bfl, acc[fm], 0, 0, 0);
                    }
                }
                __syncthreads();
            }
            // Epilogue: LDS transpose -> coalesced channel-major stores
            {
                int col = lane & 15, rowq = lane >> 4;
#pragma unroll
                for (int fm = 0; fm < 4; fm++)
#pragma unroll
                    for (int rg = 0; rg < 4; rg++)
                        Ds[(fm * 16 + rowq * 4 + rg) * 68 + wv * 16 + col] = acc[fm][rg];
            }
            __syncthreads();
            {
                int o = tid >> 2, mq0 = tid & 3;
                int oo = bn + o;
                float bias = cb[oo];
                float inv  = gma[oo] * rsqrtf(var[oo] + 1e-5f);
                float mean = mea[oo], beta = bta[oo];
                int b = bm / HWW, p0 = bm % HWW;
#pragma unroll
                for (int g = 0; g < 4; g++) {
                    int mq = mq0 + g * 4;
                    float vv[4];
#pragma unroll
                    for (int j = 0; j < 4; j++) {
                        float t = Ds[(mq * 4 + j) * 68 + o] + bias;
                        t = (t - mean) * inv + beta;
                        vv[j] = 0.5f * t * (1.0f + erff(t * 0.70710678118654752f));
                    }
                    float4 st; st.x = vv[0]; st.y = vv[1]; st.z = vv[2]; st.w = vv[3];
                    *(float4*)&y[(size_t)(b * CC + oo) * HWW + p0 + mq * 4] = st;
                }
            }
        }
    }
}

// ---------------------------------------------------------------------------
extern "C" void kernel_launch(void* const* d_in, const int* in_sizes, int n_in,
                              void* d_out, int out_size, void* d_ws, size_t ws_size,
                              hipStream_t stream) {
    const float* x   = (const float*)d_in[0];
    const float* cw  = (const float*)d_in[1];
    const float* cb  = (const float*)d_in[2];
    const float* gma = (const float*)d_in[3];
    const float* bta = (const float*)d_in[4];
    const float* mea = (const float*)d_in[5];
    const float* var = (const float*)d_in[6];
    float* out = (float*)d_out;

    float* ws = (float*)d_ws;
    float*          xt  = ws;                                   // 2,408,448 f32
    float*          sp  = ws + 2408448;                         //   802,816 f32
    unsigned short* oHh = (unsigned short*)(ws + 3211264);
    unsigned short* oHl = (unsigned short*)(ws + 4415488);
    unsigned short* oWh = (unsigned short*)(ws + 5619712);
    unsigned short* oWl = (unsigned short*)(ws + 6823936);
    unsigned short* cwh = (unsigned short*)(ws + 8028160);
    unsigned short* cwl = (unsigned short*)(ws + 8083456);
    unsigned*       bar = (unsigned*)(ws + 8138752);            // 3*14336+64 u32

    k_init<<<169, 256, 0, stream>>>(bar);
    k_mega<<<NBLK, 256, 0, stream>>>(x, cw, cb, gma, bta, mea, var, out,
                                     xt, sp, oHh, oHl, oWh, oWl, cwh, cwl, bar);
}

// Round 10
// 139.763 us; speedup vs baseline: 3.4427x; 3.4427x over previous
//
#include <hip/hip_runtime.h>
#include <hip/hip_bf16.h>
#include <math.h>

#define BB 4
#define CC 192
#define HH 56
#define WW 56
#define HWW 3136

typedef __attribute__((ext_vector_type(8))) short short8;
typedef __attribute__((ext_vector_type(4))) float f32x4;

__device__ __forceinline__ unsigned short f2b(float f) {
    __hip_bfloat16 h = __float2bfloat16(f);
    return __builtin_bit_cast(unsigned short, h);
}
__device__ __forceinline__ float b2f(unsigned short u) {
    unsigned int x = ((unsigned int)u) << 16;
    return __builtin_bit_cast(float, x);
}
__device__ __forceinline__ void fma4(float4& a, float w, const float4& x) {
    a.x += w * x.x; a.y += w * x.y; a.z += w * x.z; a.w += w * x.w;
}

// ---------------------------------------------------------------------------
// Kernel 1 (fused, all-independent work, reads only inputs):
//   blocks [0,2352):    transpose x (B,C,H,W) -> xt (B,HW,C) f32
//   blocks [2352,2784): conv_w -> split bf16, K extended to 576
//   blocks [2784,4576): scores (pair symmetry), reading x DIRECTLY
// sp layout: [half][b][pix][32] f32 (27 slots used).
// ---------------------------------------------------------------------------
__global__ __launch_bounds__(256) void k_front(const float* __restrict__ x,
                                               const float* __restrict__ cw,
                                               float* __restrict__ xt,
                                               unsigned short* __restrict__ cwh,
                                               unsigned short* __restrict__ cwl,
                                               float* __restrict__ sp) {
    __shared__ float S[2800];        // 11.2 KB union
    int tid = threadIdx.x, bid = blockIdx.x;

    if (bid < 2352) {                // ---- transpose ----
        float (*tile)[33] = (float (*)[33])S;
        int b = bid / 588, rem = bid % 588;
        int by = rem / 98, bx = rem % 98;
        int tx = tid & 31, ty = tid >> 5;
        int p0 = bx * 32, c0 = by * 32;
#pragma unroll
        for (int i = 0; i < 4; i++) {
            int c = c0 + ty + 8 * i;
            tile[ty + 8 * i][tx] = x[(b * CC + c) * HWW + p0 + tx];
        }
        __syncthreads();
#pragma unroll
        for (int i = 0; i < 4; i++) {
            int p = p0 + ty + 8 * i;
            xt[(size_t)(b * HWW + p) * CC + c0 + tx] = tile[tx][ty + 8 * i];
        }
        return;
    }
    if (bid < 2784) {                // ---- conv_w split, K=576 ----
        int i = (bid - 2352) * 256 + tid;
        if (i < CC * 576) {
            int o = i / 576, k = i % 576;
            int ks = (k >= 384) ? (k - 192) : k;
            float v = cw[o * 384 + ks];
            unsigned short hi = f2b(v);
            cwh[i] = hi;
            cwl[i] = f2b(v - b2f(hi));
        }
        return;
    }
    // ---- scores ----
    int vb = bid - 2784;             // 0..1791
    bool isH = vb < 896;
    int lid = isH ? vb : vb - 896;
    int half = lid & 1;
    int rp = (lid >> 1) & 1;         // residue pair: classes {2rp, 2rp+1}
    int cb2 = lid >> 2;              // 0..223
    int b = cb2 / 56, l0 = cb2 % 56; // column w (H) or row h (W)
    int r0 = rp * 2;
    const float SC = 0.62040705607059197f;   // sqrt(2/sqrt(27))

    if (isH) {
        // column l0: pixels pi strided by WW -> scalar gathers
        for (int idx = tid; idx < 28 * 96; idx += 256) {
            int t2 = idx / 96, c = idx % 96;
            int pi = (r0 + t2 / 14) + 4 * (t2 % 14);
            float v = x[(size_t)(b * CC + half * 96 + c) * HWW + pi * WW + l0];
            S[t2 * 100 + c] = v * SC;
        }
    } else {
        // row l0: adjacent residues r0,r0+1 -> one float2 covers both classes
        for (int idx = tid; idx < 96 * 14; idx += 256) {
            int c = idx / 14, k = idx % 14;
            float2 v = *(const float2*)&x[(size_t)(b * CC + half * 96 + c) * HWW +
                                          l0 * WW + r0 + 4 * k];
            S[k * 100 + c]        = v.x * SC;   // class 0 (pi = r0+4k)
            S[(14 + k) * 100 + c] = v.y * SC;   // class 1 (pi = r0+1+4k)
        }
    }
    __syncthreads();

    int perCls = isH ? 105 : 91;
    if (tid < 2 * perCls) {
        int cls = tid / perCls, p = tid % perCls;
        int a, bb;
        if (isH) {
            a = (int)((sqrtf((float)(8 * p + 1)) - 1.0f) * 0.5f);
            bb = p - (a * (a + 1)) / 2;
        } else {
            int ap = (int)((sqrtf((float)(8 * p + 1)) - 1.0f) * 0.5f);
            bb = p - (ap * (ap + 1)) / 2;
            a = ap + 1;
        }
        const float* pA = &S[(cls * 14 + a) * 100];
        const float* pB = &S[(cls * 14 + bb) * 100];
        float s0 = 0.f, s1 = 0.f, s2 = 0.f, s3 = 0.f;
#pragma unroll
        for (int q = 0; q < 24; q++) {
            float4 av = *(const float4*)(pA + q * 4);
            float4 bv = *(const float4*)(pB + q * 4);
            s0 += __builtin_amdgcn_rcpf(__expf(av.x * bv.x) + 1.0f);
            s1 += __builtin_amdgcn_rcpf(__expf(av.y * bv.y) + 1.0f);
            s2 += __builtin_amdgcn_rcpf(__expf(av.z * bv.z) + 1.0f);
            s3 += __builtin_amdgcn_rcpf(__expf(av.w * bv.w) + 1.0f);
        }
        float s = 96.0f - 2.0f * (s0 + s1 + s2 + s3);   // sum_c tanh
        int r = r0 + cls;
        size_t base = (size_t)(half * BB + b) * HWW;
        if (isH) {
            int i1 = a - bb;
            int h1 = r + 4 * a, h2 = r + 4 * bb;
            sp[(base + h1 * WW + l0) * 32 + i1] = s;
            if (a != bb) sp[(base + h2 * WW + l0) * 32 + (14 - i1)] = s;
        } else {
            int d = a - bb;                        // 1..13
            int w1 = r + 4 * a, w2 = r + 4 * bb;
            sp[(base + l0 * WW + w1) * 32 + 14 + (d - 1)] = s;
            sp[(base + l0 * WW + w2) * 32 + 14 + (13 - d)] = s;
        }
    }
}

// ---------------------------------------------------------------------------
// Kernel 2: softmax + weighted accumulation (identical to R7).
// blocks [0,224): columns -> oHh/oHl; [224,448): rows -> oWh/oWl (split bf16).
// ---------------------------------------------------------------------------
__global__ __launch_bounds__(192) void k_acc(const float* __restrict__ xt,
                                             const float* __restrict__ sp,
                                             unsigned short* __restrict__ oHh,
                                             unsigned short* __restrict__ oHl,
                                             unsigned short* __restrict__ oWh,
                                             unsigned short* __restrict__ oWl) {
    __shared__ float Wt[14 * 56];
    int bid = blockIdx.x, tid = threadIdx.x;
    bool isH = bid < 224;
    int lid = isH ? bid : bid - 224;
    int b = lid / 56, l0 = lid % 56;

    if (tid < 56) {
        int pix = isH ? (tid * WW + l0) : (l0 * WW + tid);
        const float4* p0 = (const float4*)&sp[((size_t)(0 * BB + b) * HWW + pix) * 32];
        const float4* p1 = (const float4*)&sp[((size_t)(1 * BB + b) * HWW + pix) * 32];
        float sc[28];
#pragma unroll
        for (int j = 0; j < 7; j++) {
            float4 u = p0[j], v = p1[j];
            sc[4 * j + 0] = u.x + v.x; sc[4 * j + 1] = u.y + v.y;
            sc[4 * j + 2] = u.z + v.z; sc[4 * j + 3] = u.w + v.w;
        }
        float mx = -1e30f;
#pragma unroll
        for (int s = 0; s < 27; s++) mx = fmaxf(mx, sc[s]);
        float sum = 0.f;
#pragma unroll
        for (int s = 0; s < 27; s++) { sc[s] = __expf(sc[s] - mx); sum += sc[s]; }
        float inv = __builtin_amdgcn_rcpf(sum);
        if (isH) {
#pragma unroll
            for (int i = 0; i < 14; i++) Wt[i * 56 + tid] = sc[i] * inv;
        } else {
#pragma unroll
            for (int j = 0; j < 13; j++) Wt[j * 56 + tid] = sc[14 + j] * inv;
        }
    }
    __syncthreads();
    {
        int r = tid & 3, q = tid >> 2;     // class, channel-quad
        float4 in[14];
#pragma unroll
        for (int t = 0; t < 14; t++) {
            int pix = isH ? ((r + 4 * t) * WW + l0) : (l0 * WW + (r + 4 * t));
            in[t] = *(const float4*)(xt + (size_t)(b * HWW + pix) * CC + q * 4);
        }
        float4 acc[14] = {};
        if (isH) {
#pragma unroll
            for (int i = 0; i < 14; i++)
#pragma unroll
                for (int a = 0; a < 14; a++)
                    fma4(acc[a], Wt[i * 56 + (r + 4 * a)], in[(a - i + 14) % 14]);
        } else {
#pragma unroll
            for (int j = 0; j < 13; j++)
#pragma unroll
                for (int a = 0; a < 14; a++)
                    fma4(acc[a], Wt[j * 56 + (r + 4 * a)], in[(a - j - 1 + 14) % 14]);
        }
        unsigned short* dh = isH ? oHh : oWh;
        unsigned short* dl = isH ? oHl : oWl;
#pragma unroll
        for (int a = 0; a < 14; a++) {
            int pix = isH ? ((r + 4 * a) * WW + l0) : (l0 * WW + (r + 4 * a));
            size_t o = (size_t)(b * HWW + pix) * CC + q * 4;
            ushort4 hi4, lo4;
            hi4.x = f2b(acc[a].x); lo4.x = f2b(acc[a].x - b2f(hi4.x));
            hi4.y = f2b(acc[a].y); lo4.y = f2b(acc[a].y - b2f(hi4.y));
            hi4.z = f2b(acc[a].z); lo4.z = f2b(acc[a].z - b2f(hi4.z));
            hi4.w = f2b(acc[a].w); lo4.w = f2b(acc[a].w - b2f(hi4.w));
            *(ushort4*)(dh + o) = hi4;
            *(ushort4*)(dl + o) = lo4;
        }
    }
}

// ---------------------------------------------------------------------------
// Kernel 3: 1x1 conv, split-bf16 MFMA GEMM, A=[x|oH|oW], M=12544 N=192 K=576
// + bias + BN + exact GELU (identical to R7). Tile 64x64, K-chunk 64, 4 waves.
// ---------------------------------------------------------------------------
__global__ __launch_bounds__(256) void k_conv(const float* __restrict__ xt,
                                              const unsigned short* __restrict__ oHh,
                                              const unsigned short* __restrict__ oHl,
                                              const unsigned short* __restrict__ oWh,
                                              const unsigned short* __restrict__ oWl,
                                              const unsigned short* __restrict__ cwh,
                                              const unsigned short* __restrict__ cwl,
                                              const float* __restrict__ cb,
                                              const float* __restrict__ gma,
                                              const float* __restrict__ bta,
                                              const float* __restrict__ mea,
                                              const float* __restrict__ var,
                                              float* __restrict__ y) {
    __shared__ unsigned short AB[4 * 64 * 72];   // 36864 B
    unsigned short* Ah = AB;
    unsigned short* Al = AB + 64 * 72;
    unsigned short* Bh = AB + 2 * 64 * 72;
    unsigned short* Bl = AB + 3 * 64 * 72;
    int bm = blockIdx.x * 64, bn = blockIdx.y * 64;
    int tid = threadIdx.x, lane = tid & 63, wv = tid >> 6;

    f32x4 acc[4] = {{0,0,0,0},{0,0,0,0},{0,0,0,0},{0,0,0,0}};

    for (int kc9 = 0; kc9 < 9; kc9++) {
#pragma unroll
        for (int r2 = 0; r2 < 2; r2++) {
            int idx = tid + r2 * 256;
            int m = idx >> 3, kq = idx & 7;
            if (kc9 < 3) {
                const float* s = xt + (size_t)(bm + m) * CC + kc9 * 64 + kq * 8;
                float4 v0 = *(const float4*)s;
                float4 v1 = *(const float4*)(s + 4);
                float vv[8] = {v0.x, v0.y, v0.z, v0.w, v1.x, v1.y, v1.z, v1.w};
                unsigned short hi[8], lo[8];
#pragma unroll
                for (int e = 0; e < 8; e++) {
                    hi[e] = f2b(vv[e]);
                    lo[e] = f2b(vv[e] - b2f(hi[e]));
                }
                *(short8*)&Ah[m * 72 + kq * 8] = *(short8*)hi;
                *(short8*)&Al[m * 72 + kq * 8] = *(short8*)lo;
            } else {
                const unsigned short* sh;
                const unsigned short* sl;
                int coff;
                if (kc9 < 6) { sh = oHh; sl = oHl; coff = (kc9 - 3) * 64; }
                else         { sh = oWh; sl = oWl; coff = (kc9 - 6) * 64; }
                size_t ao = (size_t)(bm + m) * CC + coff + kq * 8;
                *(short8*)&Ah[m * 72 + kq * 8] = *(const short8*)(sh + ao);
                *(short8*)&Al[m * 72 + kq * 8] = *(const short8*)(sl + ao);
            }
            size_t bo = (size_t)(bn + m) * 576 + kc9 * 64 + kq * 8;
            *(short8*)&Bh[m * 72 + kq * 8] = *(const short8*)(cwh + bo);
            *(short8*)&Bl[m * 72 + kq * 8] = *(const short8*)(cwl + bo);
        }
        __syncthreads();
        int n0 = wv * 16;
        int k8 = lane >> 4;
        int col = lane & 15;
#pragma unroll
        for (int ks = 0; ks < 64; ks += 32) {
            int koff = ks + k8 * 8;
            short8 bfh = *(const short8*)&Bh[(n0 + col) * 72 + koff];
            short8 bfl = *(const short8*)&Bl[(n0 + col) * 72 + koff];
#pragma unroll
            for (int fm = 0; fm < 4; fm++) {
                short8 afh = *(const short8*)&Ah[(fm * 16 + col) * 72 + koff];
                short8 afl = *(const short8*)&Al[(fm * 16 + col) * 72 + koff];
                acc[fm] = __builtin_amdgcn_mfma_f32_16x16x32_bf16(afh, bfh, acc[fm], 0, 0, 0);
                acc[fm] = __builtin_amdgcn_mfma_f32_16x16x32_bf16(afl, bfh, acc[fm], 0, 0, 0);
                acc[fm] = __builtin_amdgcn_mfma_f32_16x16x32_bf16(afh, bfl, acc[fm], 0, 0, 0);
            }
        }
        __syncthreads();
    }

    // Epilogue: LDS transpose -> coalesced channel-major stores
    float* Ds = (float*)AB;
    {
        int col = lane & 15, rowq = lane >> 4;
#pragma unroll
        for (int fm = 0; fm < 4; fm++)
#pragma unroll
            for (int rg = 0; rg < 4; rg++)
                Ds[(fm * 16 + rowq * 4 + rg) * 68 + wv * 16 + col] = acc[fm][rg];
    }
    __syncthreads();
    {
        int o = tid >> 2, mq0 = tid & 3;
        int oo = bn + o;
        float bias = cb[oo];
        float inv  = gma[oo] * rsqrtf(var[oo] + 1e-5f);
        float mean = mea[oo], beta = bta[oo];
        int b = bm / HWW, p0 = bm % HWW;
#pragma unroll
        for (int g = 0; g < 4; g++) {
            int mq = mq0 + g * 4;
            float vv[4];
#pragma unroll
            for (int j = 0; j < 4; j++) {
                float t = Ds[(mq * 4 + j) * 68 + o] + bias;
                t = (t - mean) * inv + beta;
                vv[j] = 0.5f * t * (1.0f + erff(t * 0.70710678118654752f));
            }
            float4 st; st.x = vv[0]; st.y = vv[1]; st.z = vv[2]; st.w = vv[3];
            *(float4*)&y[(size_t)(b * CC + oo) * HWW + p0 + mq * 4] = st;
        }
    }
}

// ---------------------------------------------------------------------------
extern "C" void kernel_launch(void* const* d_in, const int* in_sizes, int n_in,
                              void* d_out, int out_size, void* d_ws, size_t ws_size,
                              hipStream_t stream) {
    const float* x   = (const float*)d_in[0];
    const float* cw  = (const float*)d_in[1];
    const float* cb  = (const float*)d_in[2];
    const float* gma = (const float*)d_in[3];
    const float* bta = (const float*)d_in[4];
    const float* mea = (const float*)d_in[5];
    const float* var = (const float*)d_in[6];
    float* out = (float*)d_out;

    float* ws = (float*)d_ws;
    float*          xt  = ws;                                   // 2,408,448 f32
    float*          sp  = ws + 2408448;                         //   802,816 f32
    unsigned short* oHh = (unsigned short*)(ws + 3211264);
    unsigned short* oHl = (unsigned short*)(ws + 4415488);
    unsigned short* oWh = (unsigned short*)(ws + 5619712);
    unsigned short* oWl = (unsigned short*)(ws + 6823936);
    unsigned short* cwh = (unsigned short*)(ws + 8028160);
    unsigned short* cwl = (unsigned short*)(ws + 8083456);

    k_front<<<4576, 256, 0, stream>>>(x, cw, xt, cwh, cwl, sp);
    k_acc<<<448, 192, 0, stream>>>(xt, sp, oHh, oHl, oWh, oWl);
    k_conv<<<dim3(196, 3), 256, 0, stream>>>(xt, oHh, oHl, oWh, oWl,
                                             cwh, cwl, cb, gma, bta, mea, var, out);
}

// Round 11
// 127.937 us; speedup vs baseline: 3.7609x; 1.0924x over previous
//
#include <hip/hip_runtime.h>
#include <hip/hip_bf16.h>
#include <math.h>

#define BB 4
#define CC 192
#define HH 56
#define WW 56
#define HWW 3136

typedef __attribute__((ext_vector_type(8))) short short8;
typedef __attribute__((ext_vector_type(4))) float f32x4;

__device__ __forceinline__ unsigned short f2b(float f) {
    __hip_bfloat16 h = __float2bfloat16(f);
    return __builtin_bit_cast(unsigned short, h);
}
__device__ __forceinline__ float b2f(unsigned short u) {
    unsigned int x = ((unsigned int)u) << 16;
    return __builtin_bit_cast(float, x);
}
__device__ __forceinline__ void fma4(float4& a, float w, const float4& x) {
    a.x += w * x.x; a.y += w * x.y; a.z += w * x.z; a.w += w * x.w;
}

// ---------------------------------------------------------------------------
// Kernel 1: blocks [0,2352): transpose x (B,C,H,W) -> xt (B,HW,C) f32
//           blocks [2352,2640): W' = [C1;C2] -> split bf16 (N=384, K=192)
// W'[n][k] = cw[n][k] (n<192)  |  cw[n-192][192+k] (n>=192);  cw is [o][c] o<192,c<384
// ---------------------------------------------------------------------------
__global__ __launch_bounds__(256) void k_pre(const float* __restrict__ x,
                                             const float* __restrict__ cw,
                                             float* __restrict__ xt,
                                             unsigned short* __restrict__ cwh,
                                             unsigned short* __restrict__ cwl) {
    int tid = threadIdx.x, bid = blockIdx.x;
    if (bid < 2352) {
        __shared__ float tile[32][33];
        int b = bid / 588, rem = bid % 588;
        int by = rem / 98, bx = rem % 98;
        int tx = tid & 31, ty = tid >> 5;
        int p0 = bx * 32, c0 = by * 32;
#pragma unroll
        for (int i = 0; i < 4; i++) {
            int c = c0 + ty + 8 * i;
            tile[ty + 8 * i][tx] = x[(b * CC + c) * HWW + p0 + tx];
        }
        __syncthreads();
#pragma unroll
        for (int i = 0; i < 4; i++) {
            int p = p0 + ty + 8 * i;
            xt[(size_t)(b * HWW + p) * CC + c0 + tx] = tile[tx][ty + 8 * i];
        }
    } else {
        int i = (bid - 2352) * 256 + tid;     // 288*256 = 73728 = 384*192 exact
        if (i < 384 * 192) {
            int n = i / 192, k = i % 192;
            float v = (n < 192) ? cw[n * 384 + k] : cw[(n - 192) * 384 + 192 + k];
            unsigned short hi = f2b(v);
            cwh[i] = hi;
            cwl[i] = f2b(v - b2f(hi));
        }
    }
}

// ---------------------------------------------------------------------------
// Kernel 2 (fused independent work, reads xt/cwh/cwl only):
//   blocks [0,1792):    scores (pair symmetry) -> sp [half][b][pix][32]
//   blocks [1792,2968): GEMM [u|z] = W'·x^T, M=12544, N=384, K=192, split-bf16
// ---------------------------------------------------------------------------
__global__ __launch_bounds__(256) void k_mid(const float* __restrict__ xt,
                                             const unsigned short* __restrict__ cwh,
                                             const unsigned short* __restrict__ cwl,
                                             float* __restrict__ sp,
                                             float* __restrict__ u,
                                             float* __restrict__ z) {
    __shared__ __align__(16) char smem[36864];
    int tid = threadIdx.x, bid = blockIdx.x;

    if (bid < 1792) {                 // ---------------- scores ----------------
        float* Xs = (float*)smem;     // 28 rows x 96ch (+4 pad)
        const float K2 = 0.38490017945975050f;  // 2/sqrt(27)
        bool isH = bid < 896;
        int lid = isH ? bid : bid - 896;
        int half = lid & 1;
        int rp = (lid >> 1) & 1;
        int cb2 = lid >> 2;
        int b = cb2 / 56, l0 = cb2 % 56;
        int r0 = rp * 2;

        const float* src = xt + (size_t)(b * HWW) * CC + half * 96;
        for (int idx = tid; idx < 28 * 24; idx += 256) {
            int t2 = idx / 24, cq = idx % 24;
            int pi = (r0 + t2 / 14) + 4 * (t2 % 14);
            int pix = isH ? (pi * WW + l0) : (l0 * WW + pi);
            float4 v = *(const float4*)(src + (size_t)pix * CC + cq * 4);
            *(float4*)&Xs[t2 * 100 + cq * 4] = v;
        }
        __syncthreads();

        int perCls = isH ? 105 : 91;
        if (tid < 2 * perCls) {
            int cls = tid / perCls, p = tid % perCls;
            int a, bb;
            if (isH) {
                a = (int)((sqrtf((float)(8 * p + 1)) - 1.0f) * 0.5f);
                bb = p - (a * (a + 1)) / 2;
            } else {
                int ap = (int)((sqrtf((float)(8 * p + 1)) - 1.0f) * 0.5f);
                bb = p - (ap * (ap + 1)) / 2;
                a = ap + 1;
            }
            const float* pA = &Xs[(cls * 14 + a) * 100];
            const float* pB = &Xs[(cls * 14 + bb) * 100];
            float s0 = 0.f, s1 = 0.f, s2 = 0.f, s3 = 0.f;
#pragma unroll
            for (int q = 0; q < 24; q++) {
                float4 av = *(const float4*)(pA + q * 4);
                float4 bv = *(const float4*)(pB + q * 4);
                s0 += __builtin_amdgcn_rcpf(__expf(av.x * bv.x * K2) + 1.0f);
                s1 += __builtin_amdgcn_rcpf(__expf(av.y * bv.y * K2) + 1.0f);
                s2 += __builtin_amdgcn_rcpf(__expf(av.z * bv.z * K2) + 1.0f);
                s3 += __builtin_amdgcn_rcpf(__expf(av.w * bv.w * K2) + 1.0f);
            }
            float s = 96.0f - 2.0f * (s0 + s1 + s2 + s3);   // sum_c tanh
            int r = r0 + cls;
            size_t base = (size_t)(half * BB + b) * HWW;
            if (isH) {
                int i1 = a - bb;
                int h1 = r + 4 * a, h2 = r + 4 * bb;
                sp[(base + h1 * WW + l0) * 32 + i1] = s;
                if (a != bb) sp[(base + h2 * WW + l0) * 32 + (14 - i1)] = s;
            } else {
                int d = a - bb;                        // 1..13
                int w1 = r + 4 * a, w2 = r + 4 * bb;
                sp[(base + l0 * WW + w1) * 32 + 14 + (d - 1)] = s;
                sp[(base + l0 * WW + w2) * 32 + 14 + (13 - d)] = s;
            }
        }
        return;
    }

    // ---------------- GEMM [u|z], split-bf16, tile 64x64, K=192 ----------------
    {
        unsigned short* Ah = (unsigned short*)smem;
        unsigned short* Al = Ah + 64 * 72;
        unsigned short* Bh = Ah + 2 * 64 * 72;
        unsigned short* Bl = Ah + 3 * 64 * 72;
        float* Ds = (float*)smem;
        int vb = bid - 1792;                  // 0..1175
        int bm = (vb % 196) * 64, bn = (vb / 196) * 64;
        int lane = tid & 63, wv = tid >> 6;

        f32x4 acc[4] = {{0,0,0,0},{0,0,0,0},{0,0,0,0},{0,0,0,0}};

        for (int kc = 0; kc < 3; kc++) {
#pragma unroll
            for (int r2 = 0; r2 < 2; r2++) {
                int idx = tid + r2 * 256;
                int m = idx >> 3, kq = idx & 7;
                const float* s = xt + (size_t)(bm + m) * CC + kc * 64 + kq * 8;
                float4 v0 = *(const float4*)s;
                float4 v1 = *(const float4*)(s + 4);
                float vv[8] = {v0.x, v0.y, v0.z, v0.w, v1.x, v1.y, v1.z, v1.w};
                unsigned short hi[8], lo[8];
#pragma unroll
                for (int e = 0; e < 8; e++) {
                    hi[e] = f2b(vv[e]);
                    lo[e] = f2b(vv[e] - b2f(hi[e]));
                }
                *(short8*)&Ah[m * 72 + kq * 8] = *(short8*)hi;
                *(short8*)&Al[m * 72 + kq * 8] = *(short8*)lo;
                size_t bo = (size_t)(bn + m) * 192 + kc * 64 + kq * 8;
                *(short8*)&Bh[m * 72 + kq * 8] = *(const short8*)(cwh + bo);
                *(short8*)&Bl[m * 72 + kq * 8] = *(const short8*)(cwl + bo);
            }
            __syncthreads();
            int n0 = wv * 16;
            int k8 = lane >> 4;
            int col = lane & 15;
#pragma unroll
            for (int ks = 0; ks < 64; ks += 32) {
                int koff = ks + k8 * 8;
                short8 bfh = *(const short8*)&Bh[(n0 + col) * 72 + koff];
                short8 bfl = *(const short8*)&Bl[(n0 + col) * 72 + koff];
#pragma unroll
                for (int fm = 0; fm < 4; fm++) {
                    short8 afh = *(const short8*)&Ah[(fm * 16 + col) * 72 + koff];
                    short8 afl = *(const short8*)&Al[(fm * 16 + col) * 72 + koff];
                    acc[fm] = __builtin_amdgcn_mfma_f32_16x16x32_bf16(afh, bfh, acc[fm], 0, 0, 0);
                    acc[fm] = __builtin_amdgcn_mfma_f32_16x16x32_bf16(afl, bfh, acc[fm], 0, 0, 0);
                    acc[fm] = __builtin_amdgcn_mfma_f32_16x16x32_bf16(afh, bfl, acc[fm], 0, 0, 0);
                }
            }
            __syncthreads();
        }
        // LDS transpose: Ds[m][n], stride 68
        {
            int col = lane & 15, rowq = lane >> 4;
#pragma unroll
            for (int fm = 0; fm < 4; fm++)
#pragma unroll
                for (int rg = 0; rg < 4; rg++)
                    Ds[(fm * 16 + rowq * 4 + rg) * 68 + wv * 16 + col] = acc[fm][rg];
        }
        __syncthreads();
        // Store pixel-major: u (n<192) or z (n>=192)
        {
            int c4 = tid & 15, m0 = tid >> 4;
            int cg = bn + c4 * 4;
            float* dst = (cg < 192) ? u : z;
            int cc = (cg < 192) ? cg : cg - 192;
#pragma unroll
            for (int p = 0; p < 4; p++) {
                int m = m0 + p * 16;
                float4 v = *(float4*)&Ds[m * 68 + c4 * 4];
                *(float4*)&dst[(size_t)(bm + m) * CC + cc] = v;
            }
        }
    }
}

// ---------------------------------------------------------------------------
// Kernel 3: per-column H-part: y_p = u + sum_i w_i * z(H-roll i)   (f32)
// 224 blocks (b, w), 192 threads.
// ---------------------------------------------------------------------------
__global__ __launch_bounds__(192) void k_accH(const float* __restrict__ u,
                                              const float* __restrict__ z,
                                              const float* __restrict__ sp,
                                              float* __restrict__ yp) {
    __shared__ float Wt[14 * 56];
    int bid = blockIdx.x, tid = threadIdx.x;
    int b = bid / 56, l0 = bid % 56;

    if (tid < 56) {
        int pix = tid * WW + l0;
        const float4* p0 = (const float4*)&sp[((size_t)(0 * BB + b) * HWW + pix) * 32];
        const float4* p1 = (const float4*)&sp[((size_t)(1 * BB + b) * HWW + pix) * 32];
        float sc[28];
#pragma unroll
        for (int j = 0; j < 7; j++) {
            float4 a = p0[j], v = p1[j];
            sc[4 * j + 0] = a.x + v.x; sc[4 * j + 1] = a.y + v.y;
            sc[4 * j + 2] = a.z + v.z; sc[4 * j + 3] = a.w + v.w;
        }
        float mx = -1e30f;
#pragma unroll
        for (int s = 0; s < 27; s++) mx = fmaxf(mx, sc[s]);
        float sum = 0.f;
#pragma unroll
        for (int s = 0; s < 27; s++) { sc[s] = __expf(sc[s] - mx); sum += sc[s]; }
        float inv = __builtin_amdgcn_rcpf(sum);
#pragma unroll
        for (int i = 0; i < 14; i++) Wt[i * 56 + tid] = sc[i] * inv;
    }
    __syncthreads();
    {
        int r = tid & 3, q = tid >> 2;
        float4 in[14];
#pragma unroll
        for (int t = 0; t < 14; t++) {
            int pix = (r + 4 * t) * WW + l0;
            in[t] = *(const float4*)(z + (size_t)(b * HWW + pix) * CC + q * 4);
        }
        float4 acc[14];
#pragma unroll
        for (int a = 0; a < 14; a++) {
            int pix = (r + 4 * a) * WW + l0;
            acc[a] = *(const float4*)(u + (size_t)(b * HWW + pix) * CC + q * 4);
        }
#pragma unroll
        for (int i = 0; i < 14; i++)
#pragma unroll
            for (int a = 0; a < 14; a++)
                fma4(acc[a], Wt[i * 56 + (r + 4 * a)], in[(a - i + 14) % 14]);
#pragma unroll
        for (int a = 0; a < 14; a++) {
            int pix = (r + 4 * a) * WW + l0;
            *(float4*)(yp + (size_t)(b * HWW + pix) * CC + q * 4) = acc[a];
        }
    }
}

// ---------------------------------------------------------------------------
// Kernel 4: per-row W-part + bias + BN + GELU, store y (B,C,H,W).
// 224 blocks (b, h), 192 threads.
// ---------------------------------------------------------------------------
__global__ __launch_bounds__(192) void k_accW(const float* __restrict__ yp,
                                              const float* __restrict__ z,
                                              const float* __restrict__ sp,
                                              const float* __restrict__ cb,
                                              const float* __restrict__ gma,
                                              const float* __restrict__ bta,
                                              const float* __restrict__ mea,
                                              const float* __restrict__ var,
                                              float* __restrict__ y) {
    __shared__ float Wt[14 * 56];
    __shared__ float Ys[56 * 196];
    int bid = blockIdx.x, tid = threadIdx.x;
    int b = bid / 56, l0 = bid % 56;     // row h = l0

    if (tid < 56) {
        int pix = l0 * WW + tid;
        const float4* p0 = (const float4*)&sp[((size_t)(0 * BB + b) * HWW + pix) * 32];
        const float4* p1 = (const float4*)&sp[((size_t)(1 * BB + b) * HWW + pix) * 32];
        float sc[28];
#pragma unroll
        for (int j = 0; j < 7; j++) {
            float4 a = p0[j], v = p1[j];
            sc[4 * j + 0] = a.x + v.x; sc[4 * j + 1] = a.y + v.y;
            sc[4 * j + 2] = a.z + v.z; sc[4 * j + 3] = a.w + v.w;
        }
        float mx = -1e30f;
#pragma unroll
        for (int s = 0; s < 27; s++) mx = fmaxf(mx, sc[s]);
        float sum = 0.f;
#pragma unroll
        for (int s = 0; s < 27; s++) { sc[s] = __expf(sc[s] - mx); sum += sc[s]; }
        float inv = __builtin_amdgcn_rcpf(sum);
#pragma unroll
        for (int j = 0; j < 13; j++) Wt[j * 56 + tid] = sc[14 + j] * inv;
    }
    __syncthreads();
    {
        int r = tid & 3, q = tid >> 2;
        float4 in[14];
#pragma unroll
        for (int t = 0; t < 14; t++) {
            int pix = l0 * WW + (r + 4 * t);
            in[t] = *(const float4*)(z + (size_t)(b * HWW + pix) * CC + q * 4);
        }
        float4 acc[14];
#pragma unroll
        for (int a = 0; a < 14; a++) {
            int pix = l0 * WW + (r + 4 * a);
            acc[a] = *(const float4*)(yp + (size_t)(b * HWW + pix) * CC + q * 4);
        }
#pragma unroll
        for (int j = 0; j < 13; j++)
#pragma unroll
            for (int a = 0; a < 14; a++)
                fma4(acc[a], Wt[j * 56 + (r + 4 * a)], in[(a - j - 1 + 14) % 14]);

        // bias + BN + GELU on 4 channels (q*4..q*4+3), stage into Ys[w][c]
        float4 bias4 = *(const float4*)&cb[q * 4];
        float4 g4 = *(const float4*)&gma[q * 4];
        float4 bt4 = *(const float4*)&bta[q * 4];
        float4 me4 = *(const float4*)&mea[q * 4];
        float4 va4 = *(const float4*)&var[q * 4];
        float inv0 = g4.x * rsqrtf(va4.x + 1e-5f);
        float inv1 = g4.y * rsqrtf(va4.y + 1e-5f);
        float inv2 = g4.z * rsqrtf(va4.z + 1e-5f);
        float inv3 = g4.w * rsqrtf(va4.w + 1e-5f);
#pragma unroll
        for (int a = 0; a < 14; a++) {
            int w = r + 4 * a;
            float4 t = acc[a];
            t.x = (t.x + bias4.x - me4.x) * inv0 + bt4.x;
            t.y = (t.y + bias4.y - me4.y) * inv1 + bt4.y;
            t.z = (t.z + bias4.z - me4.z) * inv2 + bt4.z;
            t.w = (t.w + bias4.w - me4.w) * inv3 + bt4.w;
            t.x = 0.5f * t.x * (1.0f + erff(t.x * 0.70710678118654752f));
            t.y = 0.5f * t.y * (1.0f + erff(t.y * 0.70710678118654752f));
            t.z = 0.5f * t.z * (1.0f + erff(t.z * 0.70710678118654752f));
            t.w = 0.5f * t.w * (1.0f + erff(t.w * 0.70710678118654752f));
            *(float4*)&Ys[w * 196 + q * 4] = t;
        }
    }
    __syncthreads();
    {
        int c = tid;   // 0..191
#pragma unroll
        for (int w4 = 0; w4 < 14; w4++) {
            float4 v;
            v.x = Ys[(w4 * 4 + 0) * 196 + c];
            v.y = Ys[(w4 * 4 + 1) * 196 + c];
            v.z = Ys[(w4 * 4 + 2) * 196 + c];
            v.w = Ys[(w4 * 4 + 3) * 196 + c];
            *(float4*)&y[(size_t)(b * CC + c) * HWW + l0 * WW + w4 * 4] = v;
        }
    }
}

// ---------------------------------------------------------------------------
extern "C" void kernel_launch(void* const* d_in, const int* in_sizes, int n_in,
                              void* d_out, int out_size, void* d_ws, size_t ws_size,
                              hipStream_t stream) {
    const float* x   = (const float*)d_in[0];
    const float* cw  = (const float*)d_in[1];
    const float* cb  = (const float*)d_in[2];
    const float* gma = (const float*)d_in[3];
    const float* bta = (const float*)d_in[4];
    const float* mea = (const float*)d_in[5];
    const float* var = (const float*)d_in[6];
    float* out = (float*)d_out;

    float* ws = (float*)d_ws;
    float*          xt  = ws;                                   // 2,408,448
    float*          sp  = ws + 2408448;                         //   802,816
    float*          u   = ws + 3211264;                         // 2,408,448
    float*          z   = ws + 5619712;                         // 2,408,448
    float*          yp  = ws + 8028160;                         // 2,408,448
    unsigned short* cwh = (unsigned short*)(ws + 10436608);     //    73,728 us
    unsigned short* cwl = (unsigned short*)(ws + 10473472);

    k_pre<<<2640, 256, 0, stream>>>(x, cw, xt, cwh, cwl);
    k_mid<<<2968, 256, 0, stream>>>(xt, cwh, cwl, sp, u, z);
    k_accH<<<224, 192, 0, stream>>>(u, z, sp, yp);
    k_accW<<<224, 192, 0, stream>>>(yp, z, sp, cb, gma, bta, mea, var, out);
}